// Round 1
// baseline (3832.655 us; speedup 1.0000x reference)
//
#include <hip/hip_runtime.h>
#include <math.h>

#define NB 16
#define P 1024
#define EPSV 1e-3f
#define INV_EPS 1000.0f
#define LOGEPS 1e-8f
#define NCH 32   // row chunks per batch for v-partial
#define RPC 32   // rows per chunk (NCH*RPC == P)
#define NEG_BIG -1e30f

// Online logsumexp update in "raw" units: tracks m = running max of t,
// s = sum of exp((t - m)/EPS). Final lse = m/EPS + log(s).
__device__ __forceinline__ void olse(float& m, float& s, float t) {
  if (t > m) { s = s * __expf((m - t) * INV_EPS) + 1.0f; m = t; }
  else       { s += __expf((t - m) * INV_EPS); }
}

__global__ __launch_bounds__(256) void k_init(const float* __restrict__ mu,
                                              const float* __restrict__ nu,
                                              float* __restrict__ elmu,
                                              float* __restrict__ elnu,
                                              float* __restrict__ u) {
  int idx = blockIdx.x * 256 + threadIdx.x;
  elmu[idx] = EPSV * __logf(mu[idx] + LOGEPS);
  elnu[idx] = EPSV * __logf(nu[idx] + LOGEPS);
  u[idx] = 1.0f;  // u0 = ones; v0 never actually used (cancels in update)
}

// Column-wise partial LSE over a 32-row chunk. Thread t owns cols 4t..4t+3.
// grid = NB*NCH blocks of 256.
__global__ __launch_bounds__(256) void k_vpart(const float* __restrict__ C,
                                               const float* __restrict__ u,
                                               float* __restrict__ pm,
                                               float* __restrict__ ps) {
  int n = blockIdx.x / NCH, ch = blockIdx.x % NCH;
  int col = threadIdx.x * 4;
  const float* Cn = C + (size_t)n * P * P;
  const float* un = u + n * P;
  float m0 = NEG_BIG, m1 = NEG_BIG, m2 = NEG_BIG, m3 = NEG_BIG;
  float s0 = 0.f, s1 = 0.f, s2 = 0.f, s3 = 0.f;
  int i0 = ch * RPC;
  for (int r = 0; r < RPC; ++r) {
    int i = i0 + r;
    float ui = un[i];
    float4 c = *(const float4*)(Cn + (size_t)i * P + col);
    olse(m0, s0, ui - c.x);
    olse(m1, s1, ui - c.y);
    olse(m2, s2, ui - c.z);
    olse(m3, s3, ui - c.w);
  }
  size_t o = (size_t)(n * NCH + ch) * P + col;
  *(float4*)(pm + o) = make_float4(m0, m1, m2, m3);
  *(float4*)(ps + o) = make_float4(s0, s1, s2, s3);
}

// Combine NCH partials per column -> v. grid = NB*4 blocks of 256.
__global__ __launch_bounds__(256) void k_vcomb(const float* __restrict__ elnu,
                                               const float* __restrict__ pm,
                                               const float* __restrict__ ps,
                                               float* __restrict__ v) {
  int n = blockIdx.x / 4;
  int col = (blockIdx.x % 4) * 256 + threadIdx.x;
  float M = NEG_BIG;
  for (int ch = 0; ch < NCH; ++ch)
    M = fmaxf(M, pm[(size_t)(n * NCH + ch) * P + col]);
  float S = 0.0f;
  for (int ch = 0; ch < NCH; ++ch) {
    size_t o = (size_t)(n * NCH + ch) * P + col;
    S += ps[o] * __expf((pm[o] - M) * INV_EPS);
  }
  v[n * P + col] = elnu[n * P + col] - M - EPSV * __logf(S);
}

// Row-wise LSE: each wave reduces one row at a time (4 rows per wave).
// grid = NB*64 blocks of 256 (16 rows per block).
__global__ __launch_bounds__(256) void k_uupd(const float* __restrict__ C,
                                              const float* __restrict__ v,
                                              const float* __restrict__ elmu,
                                              float* __restrict__ u) {
  int n = blockIdx.x >> 6, rb = blockIdx.x & 63;
  int wave = threadIdx.x >> 6, lane = threadIdx.x & 63;
  const float* Cn = C + (size_t)n * P * P;
  const float* vn = v + n * P;
  for (int rr = 0; rr < 4; ++rr) {
    int i = rb * 16 + rr * 4 + wave;
    const float* Ci = Cn + (size_t)i * P;
    float m = NEG_BIG, s = 0.0f;
    for (int chunk = 0; chunk < 4; ++chunk) {
      int col = chunk * 256 + lane * 4;
      float4 c = *(const float4*)(Ci + col);
      float4 vv = *(const float4*)(vn + col);
      olse(m, s, vv.x - c.x);
      olse(m, s, vv.y - c.y);
      olse(m, s, vv.z - c.z);
      olse(m, s, vv.w - c.w);
    }
    // wave-level (m,s) combine across 64 lanes
    for (int off = 1; off < 64; off <<= 1) {
      float mo = __shfl_xor(m, off);
      float so = __shfl_xor(s, off);
      float M = fmaxf(m, mo);
      s = s * __expf((m - M) * INV_EPS) + so * __expf((mo - M) * INV_EPS);
      m = M;
    }
    if (lane == 0)
      u[n * P + i] = elmu[n * P + i] - m - EPSV * __logf(s);
  }
}

// pi = exp((u_i + v_j - C_ij)/EPS) written to out+16; cost_n = sum(pi*C).
// grid = NB*NCH blocks of 256.
__global__ __launch_bounds__(256) void k_picost(const float* __restrict__ C,
                                                const float* __restrict__ u,
                                                const float* __restrict__ v,
                                                float* __restrict__ out) {
  int n = blockIdx.x / NCH, ch = blockIdx.x % NCH;
  int col = threadIdx.x * 4;
  const float* Cn = C + (size_t)n * P * P;
  const float* un = u + n * P;
  const float* vn = v + n * P;
  float* pi = out + 16 + (size_t)n * P * P;
  float4 vv = *(const float4*)(vn + col);
  float acc = 0.0f;
  int i0 = ch * RPC;
  for (int r = 0; r < RPC; ++r) {
    int i = i0 + r;
    float ui = un[i];
    float4 c = *(const float4*)(Cn + (size_t)i * P + col);
    float4 p;
    p.x = __expf((ui + vv.x - c.x) * INV_EPS);
    p.y = __expf((ui + vv.y - c.y) * INV_EPS);
    p.z = __expf((ui + vv.z - c.z) * INV_EPS);
    p.w = __expf((ui + vv.w - c.w) * INV_EPS);
    *(float4*)(pi + (size_t)i * P + col) = p;
    acc += p.x * c.x + p.y * c.y + p.z * c.z + p.w * c.w;
  }
  for (int off = 1; off < 64; off <<= 1) acc += __shfl_xor(acc, off);
  __shared__ float red[4];
  int wave = threadIdx.x >> 6, lane = threadIdx.x & 63;
  if (lane == 0) red[wave] = acc;
  __syncthreads();
  if (threadIdx.x == 0) atomicAdd(out + n, red[0] + red[1] + red[2] + red[3]);
}

extern "C" void kernel_launch(void* const* d_in, const int* in_sizes, int n_in,
                              void* d_out, int out_size, void* d_ws, size_t ws_size,
                              hipStream_t stream) {
  const float* mu = (const float*)d_in[0];
  const float* nu = (const float*)d_in[1];
  const float* C  = (const float*)d_in[2];
  float* out = (float*)d_out;
  float* ws = (float*)d_ws;

  float* u    = ws;                    // NB*P
  float* v    = ws + NB * P;           // NB*P
  float* elmu = ws + 2 * NB * P;       // NB*P
  float* elnu = ws + 3 * NB * P;       // NB*P
  float* pm   = ws + 4 * NB * P;       // NB*NCH*P
  float* ps   = pm + (size_t)NB * NCH * P;  // NB*NCH*P
  // total ws: (4*16K + 2*512K) floats = ~4.25 MB

  hipMemsetAsync(d_out, 0, NB * sizeof(float), stream);  // zero cost accumulators
  k_init<<<NB * P / 256, 256, 0, stream>>>(mu, nu, elmu, elnu, u);
  for (int it = 0; it < 100; ++it) {
    k_vpart<<<NB * NCH, 256, 0, stream>>>(C, u, pm, ps);
    k_vcomb<<<NB * 4, 256, 0, stream>>>(elnu, pm, ps, v);
    k_uupd<<<NB * 64, 256, 0, stream>>>(C, v, elmu, u);
  }
  k_picost<<<NB * NCH, 256, 0, stream>>>(C, u, v, out);
}